// Round 1
// baseline (10494.025 us; speedup 1.0000x reference)
//
#include <hip/hip_runtime.h>
#include <math.h>

// ---------------- constants ----------------
#define B_    1024
#define C1    48
#define P1S   196      // 14*14 after pool1
#define C2    128
#define C3    256
#define S3    49       // 7*7 after pool2
#define FEAT  12544    // 256*7*7
#define N4    2048
#define NOUT  10
#define EPSV  1e-5

__device__ __forceinline__ float sgn(float v){ return (v>0.f)?1.f:((v<0.f)?-1.f:0.f); }

// ---------------- K1: conv1 (binarized in & w) + bias + maxpool2 ----------------
__global__ __launch_bounds__(256) void k_conv1_pool(const float* __restrict__ x,
                                                    const float* __restrict__ w1,
                                                    const float* __restrict__ b1,
                                                    float* __restrict__ p1){
  int idx = blockIdx.x*256 + threadIdx.x;
  if (idx >= B_*C1*P1S) return;
  int p = idx % P1S; int c = (idx/P1S) % C1; int b = idx/(P1S*C1);
  int y = p/14, xq = p%14;
  const float* xb = x + (size_t)b*784;
  float w[9];
#pragma unroll
  for (int k=0;k<9;k++) w[k] = sgn(w1[c*9+k]);
  float sx[4][4];
#pragma unroll
  for (int dy=0; dy<4; dy++){
    int iy = 2*y-1+dy;
#pragma unroll
    for (int dx=0; dx<4; dx++){
      int ix = 2*xq-1+dx;
      sx[dy][dx] = (iy>=0 && iy<28 && ix>=0 && ix<28) ? sgn(xb[iy*28+ix]) : 0.f;
    }
  }
  float best = -1e30f;
#pragma unroll
  for (int py=0;py<2;py++)
#pragma unroll
    for (int px=0;px<2;px++){
      float acc = 0.f;
#pragma unroll
      for (int ky=0;ky<3;ky++)
#pragma unroll
        for (int kx=0;kx<3;kx++)
          acc += sx[py+ky][px+kx]*w[ky*3+kx];
      best = fmaxf(best, acc);
    }
  p1[idx] = best + b1[c];
}

// ---------------- stats: per-channel sum / sumsq (double) ----------------
// src viewed as [B][C][S]; grid = (C, GY)
__global__ __launch_bounds__(256) void k_stats(const float* __restrict__ src,
                                               double* __restrict__ sum,
                                               double* __restrict__ sumsq,
                                               int Bn, int C, int S){
  int c = blockIdx.x;
  long NS = (long)Bn*S;
  double a=0.0, a2=0.0;
  long stride = (long)gridDim.y*blockDim.x;
  for (long i = (long)blockIdx.y*blockDim.x + threadIdx.x; i < NS; i += stride){
    long b = i / S, s = i % S;
    double v = (double)src[((size_t)b*C + c)*S + s];
    a += v; a2 += v*v;
  }
  __shared__ double rs[256], rs2[256];
  rs[threadIdx.x]=a; rs2[threadIdx.x]=a2;
  __syncthreads();
  for (int off=128; off>0; off>>=1){
    if (threadIdx.x < off){ rs[threadIdx.x]+=rs[threadIdx.x+off]; rs2[threadIdx.x]+=rs2[threadIdx.x+off]; }
    __syncthreads();
  }
  if (threadIdx.x==0){ atomicAdd(&sum[c], rs[0]); atomicAdd(&sumsq[c], rs2[0]); }
}

// ---------------- bn params: scale/shift from sums ----------------
__global__ void k_bnparams(const double* __restrict__ sum, const double* __restrict__ sumsq,
                           const float* __restrict__ g, const float* __restrict__ be,
                           float* __restrict__ scale, float* __restrict__ shift,
                           int C, double invN){
  int c = blockIdx.x*blockDim.x + threadIdx.x;
  if (c >= C) return;
  double m   = sum[c]*invN;
  double var = sumsq[c]*invN - m*m;
  double s   = (double)g[c] / sqrt(var + EPSV);
  scale[c] = (float)s;
  shift[c] = (float)((double)be[c] - m*s);
}

// ---------------- normalize in place: mode 0 = sign(bn), mode 1 = htanh(bn) ----------------
__global__ __launch_bounds__(256) void k_norm(float* __restrict__ buf,
                                              const float* __restrict__ scale,
                                              const float* __restrict__ shift,
                                              int C, int S, int total, int mode){
  int i = blockIdx.x*256 + threadIdx.x;
  if (i >= total) return;
  int c = (i / S) % C;
  float v = buf[i]*scale[c] + shift[c];
  buf[i] = (mode==0) ? sgn(v) : fminf(fmaxf(v,-1.f),1.f);
}

// ---------------- conv2: 48ch 14x14 -> 128ch 14x14 ----------------
#define OCT2 8
__global__ __launch_bounds__(256) void k_conv2(const float* __restrict__ s1,
                                               const float* __restrict__ w2,
                                               const float* __restrict__ b2,
                                               float* __restrict__ c2){
  __shared__ float sIn[C1*P1S];       // 48*196 = 37.6KB
  __shared__ float sW[OCT2*432];      // 13.8KB
  int ocb = blockIdx.x*OCT2;          // gridDim.x = 16
  int b   = blockIdx.y;
  const float* inb = s1 + (size_t)b*C1*P1S;
  for (int i=threadIdx.x; i<C1*P1S; i+=256) sIn[i] = inb[i];
  for (int i=threadIdx.x; i<OCT2*432; i+=256){
    int o = i/432, r = i%432;
    sW[i] = sgn(w2[(size_t)(ocb+o)*432 + r]);
  }
  __syncthreads();
  int p = threadIdx.x;
  if (p < P1S){
    int y = p/14, xq = p%14;
    float acc[OCT2];
#pragma unroll
    for (int o=0;o<OCT2;o++) acc[o]=0.f;
    for (int ic=0; ic<C1; ic++){
      const float* ip = &sIn[ic*P1S];
      const float* wp = &sW[ic*9];
#pragma unroll
      for (int ky=0;ky<3;ky++){
        int iy = y+ky-1;
        if (iy<0 || iy>=14) continue;
#pragma unroll
        for (int kx=0;kx<3;kx++){
          int ix = xq+kx-1;
          if (ix<0 || ix>=14) continue;
          float v = ip[iy*14+ix];
#pragma unroll
          for (int o=0;o<OCT2;o++) acc[o] += v*wp[o*432 + ky*3+kx];
        }
      }
    }
    size_t base = ((size_t)b*C2 + ocb)*P1S + p;
#pragma unroll
    for (int o=0;o<OCT2;o++) c2[base + (size_t)o*P1S] = acc[o] + b2[ocb+o];
  }
}

// ---------------- conv3 + maxpool2: 128ch 14x14 -> 256ch 7x7 ----------------
#define OCT3 16
__global__ __launch_bounds__(256) void k_conv3_pool(const float* __restrict__ s2,
                                                    const float* __restrict__ w3,
                                                    const float* __restrict__ b3,
                                                    float* __restrict__ p3){
  __shared__ float sIn[32*P1S];       // 25.1KB (ic quarter)
  __shared__ float sW[OCT3*288];      // 18.4KB
  __shared__ float sPool[OCT3][P1S];  // 12.5KB
  int ocb = blockIdx.x*OCT3;          // gridDim.x = 16
  int b   = blockIdx.y;
  int p = threadIdx.x;
  int y = p/14, xq = p%14;
  float acc[OCT3];
#pragma unroll
  for (int o=0;o<OCT3;o++) acc[o]=0.f;
  for (int icq=0; icq<4; icq++){
    __syncthreads();
    const float* inb = s2 + ((size_t)b*C2 + icq*32)*P1S;
    for (int i=threadIdx.x; i<32*P1S; i+=256) sIn[i] = inb[i];
    for (int i=threadIdx.x; i<OCT3*288; i+=256){
      int o = i/288, r = i%288;
      sW[i] = sgn(w3[(size_t)(ocb+o)*1152 + icq*288 + r]);
    }
    __syncthreads();
    if (p < P1S){
      for (int ic=0; ic<32; ic++){
        const float* ip = &sIn[ic*P1S];
        const float* wp = &sW[ic*9];
#pragma unroll
        for (int ky=0;ky<3;ky++){
          int iy = y+ky-1;
          if (iy<0 || iy>=14) continue;
#pragma unroll
          for (int kx=0;kx<3;kx++){
            int ix = xq+kx-1;
            if (ix<0 || ix>=14) continue;
            float v = ip[iy*14+ix];
#pragma unroll
            for (int o=0;o<OCT3;o++) acc[o] += v*wp[o*288 + ky*3+kx];
          }
        }
      }
    }
  }
  __syncthreads();
  if (p < P1S){
#pragma unroll
    for (int o=0;o<OCT3;o++) sPool[o][p] = acc[o];
  }
  __syncthreads();
  for (int t=threadIdx.x; t<S3*OCT3; t+=256){
    int o = t/S3, cell = t%S3;
    int cy = cell/7, cx = cell%7;
    int p0 = (2*cy)*14 + 2*cx;
    float m0 = fmaxf(sPool[o][p0],    sPool[o][p0+1]);
    float m1 = fmaxf(sPool[o][p0+14], sPool[o][p0+15]);
    p3[((size_t)b*C3 + ocb+o)*S3 + cell] = fmaxf(m0,m1) + b3[ocb+o];
  }
}

// ---------------- fc1: [1024,12544] x sign(wf1)[2048,12544]^T ----------------
#define BM 128
#define BN 128
#define BK 16
__global__ __launch_bounds__(256) void k_fc1(const float* __restrict__ A,
                                             const float* __restrict__ W,
                                             const float* __restrict__ bias,
                                             float* __restrict__ Cc){
  __shared__ float As[BK][BM];
  __shared__ float Bs[BK][BN];
  int bn = blockIdx.x*BN;   // gridDim.x = 16
  int bm = blockIdx.y*BM;   // gridDim.y = 8
  int tid = threadIdx.x;
  int tx = tid%16, ty = tid/16;
  float acc[8][8];
#pragma unroll
  for (int i=0;i<8;i++)
#pragma unroll
    for (int j=0;j<8;j++) acc[i][j]=0.f;
  for (int k0=0; k0<FEAT; k0+=BK){
    __syncthreads();
    for (int i=tid; i<BM*BK; i+=256){
      int m = i/BK, kk = i%BK;
      As[kk][m] = A[(size_t)(bm+m)*FEAT + k0+kk];
    }
    for (int i=tid; i<BN*BK; i+=256){
      int n = i/BK, kk = i%BK;
      Bs[kk][n] = sgn(W[(size_t)(bn+n)*FEAT + k0+kk]);
    }
    __syncthreads();
#pragma unroll
    for (int kk=0; kk<BK; kk++){
      float a8[8], b8[8];
#pragma unroll
      for (int j=0;j<8;j++){ a8[j]=As[kk][ty*8+j]; b8[j]=Bs[kk][tx*8+j]; }
#pragma unroll
      for (int i=0;i<8;i++)
#pragma unroll
        for (int j=0;j<8;j++) acc[i][j] += a8[i]*b8[j];
    }
  }
#pragma unroll
  for (int i=0;i<8;i++){
    size_t m = bm + ty*8 + i;
#pragma unroll
    for (int j=0;j<8;j++){
      int n = bn + tx*8 + j;
      Cc[m*N4 + n] = acc[i][j] + bias[n];
    }
  }
}

// ---------------- fc2 + log_softmax ----------------
__global__ __launch_bounds__(256) void k_fc2_lsm(const float* __restrict__ h,
                                                 const float* __restrict__ W,
                                                 const float* __restrict__ bias,
                                                 float* __restrict__ out){
  int b = blockIdx.x;
  const float* hb = h + (size_t)b*N4;
  float acc[NOUT];
#pragma unroll
  for (int o=0;o<NOUT;o++) acc[o]=0.f;
  for (int k=threadIdx.x; k<N4; k+=256){
    float v = hb[k];
#pragma unroll
    for (int o=0;o<NOUT;o++) acc[o] += v*W[o*N4+k];
  }
  __shared__ float red[4][NOUT];
  int wv = threadIdx.x>>6, lane = threadIdx.x&63;
#pragma unroll
  for (int o=0;o<NOUT;o++){
    float r = acc[o];
    for (int off=32; off>0; off>>=1) r += __shfl_down(r, off);
    if (lane==0) red[wv][o]=r;
  }
  __syncthreads();
  if (threadIdx.x==0){
    float lg[NOUT], mx=-1e30f;
#pragma unroll
    for (int o=0;o<NOUT;o++){ lg[o]=red[0][o]+red[1][o]+red[2][o]+red[3][o]+bias[o]; mx=fmaxf(mx,lg[o]); }
    float se=0.f;
#pragma unroll
    for (int o=0;o<NOUT;o++) se += expf(lg[o]-mx);
    float lse = mx + logf(se);
#pragma unroll
    for (int o=0;o<NOUT;o++) out[(size_t)b*NOUT+o] = lg[o]-lse;
  }
}

// ---------------- launch ----------------
extern "C" void kernel_launch(void* const* d_in, const int* in_sizes, int n_in,
                              void* d_out, int out_size, void* d_ws, size_t ws_size,
                              hipStream_t stream){
  (void)in_sizes; (void)n_in; (void)out_size; (void)ws_size;
  const float* x   = (const float*)d_in[0];
  const float* w1  = (const float*)d_in[1];
  const float* b1  = (const float*)d_in[2];
  const float* g1  = (const float*)d_in[3];
  const float* be1 = (const float*)d_in[4];
  const float* w2  = (const float*)d_in[5];
  const float* b2  = (const float*)d_in[6];
  const float* g2  = (const float*)d_in[7];
  const float* be2 = (const float*)d_in[8];
  const float* w3  = (const float*)d_in[9];
  const float* b3  = (const float*)d_in[10];
  const float* g3  = (const float*)d_in[11];
  const float* be3 = (const float*)d_in[12];
  const float* wf1 = (const float*)d_in[13];
  const float* bf1 = (const float*)d_in[14];
  const float* g4  = (const float*)d_in[15];
  const float* be4 = (const float*)d_in[16];
  const float* wf2 = (const float*)d_in[17];
  const float* bf2 = (const float*)d_in[18];
  float* out = (float*)d_out;

  char* w = (char*)d_ws;
  double* sum   = (double*)w;               // 2048 doubles
  double* sumsq = sum + 2048;               // 2048 doubles   (ends at 32768B)
  float*  scale = (float*)(w + 32768);      // 2048 floats
  float*  shift = scale + 2048;             //               (ends at 49152B)
  float*  p1 = (float*)(w + 65536);                 // 9,633,792 f
  float*  c2 = p1 + (size_t)B_*C1*P1S;              // 25,690,112 f
  float*  p3 = c2 + (size_t)B_*C2*P1S;              // 12,845,056 f
  float*  f1 = p1;                                  // reuse (p1 dead after conv2)

  // layer 1: conv1+pool -> bn stats -> sign
  k_conv1_pool<<<dim3((B_*C1*P1S+255)/256), 256, 0, stream>>>(x, w1, b1, p1);
  hipMemsetAsync(sum, 0, 2048*2*sizeof(double), stream);
  k_stats<<<dim3(C1,64), 256, 0, stream>>>(p1, sum, sumsq, B_, C1, P1S);
  k_bnparams<<<dim3(1), 256, 0, stream>>>(sum, sumsq, g1, be1, scale, shift, C1, 1.0/((double)B_*P1S));
  k_norm<<<dim3((B_*C1*P1S+255)/256), 256, 0, stream>>>(p1, scale, shift, C1, P1S, B_*C1*P1S, 0);

  // layer 2: conv2 -> bn stats -> sign
  k_conv2<<<dim3(16, B_), 256, 0, stream>>>(p1, w2, b2, c2);
  hipMemsetAsync(sum, 0, 2048*2*sizeof(double), stream);
  k_stats<<<dim3(C2,32), 256, 0, stream>>>(c2, sum, sumsq, B_, C2, P1S);
  k_bnparams<<<dim3(1), 256, 0, stream>>>(sum, sumsq, g2, be2, scale, shift, C2, 1.0/((double)B_*P1S));
  k_norm<<<dim3((B_*C2*P1S+255)/256), 256, 0, stream>>>(c2, scale, shift, C2, P1S, B_*C2*P1S, 0);

  // layer 3: conv3+pool -> bn stats -> sign
  k_conv3_pool<<<dim3(16, B_), 256, 0, stream>>>(c2, w3, b3, p3);
  hipMemsetAsync(sum, 0, 2048*2*sizeof(double), stream);
  k_stats<<<dim3(C3,16), 256, 0, stream>>>(p3, sum, sumsq, B_, C3, S3);
  k_bnparams<<<dim3(1), 256, 0, stream>>>(sum, sumsq, g3, be3, scale, shift, C3, 1.0/((double)B_*S3));
  k_norm<<<dim3((B_*C3*S3+255)/256), 256, 0, stream>>>(p3, scale, shift, C3, S3, B_*C3*S3, 0);

  // fc1 -> bn1d stats -> htanh
  k_fc1<<<dim3(16, 8), 256, 0, stream>>>(p3, wf1, bf1, f1);
  hipMemsetAsync(sum, 0, 2048*2*sizeof(double), stream);
  k_stats<<<dim3(N4,4), 256, 0, stream>>>(f1, sum, sumsq, B_, N4, 1);
  k_bnparams<<<dim3(8), 256, 0, stream>>>(sum, sumsq, g4, be4, scale, shift, N4, 1.0/(double)B_);
  k_norm<<<dim3((B_*N4+255)/256), 256, 0, stream>>>(f1, scale, shift, N4, 1, B_*N4, 1);

  // fc2 + log_softmax
  k_fc2_lsm<<<dim3(B_), 256, 0, stream>>>(f1, wf2, bf2, out);
}

// Round 2
// 1083.714 us; speedup vs baseline: 9.6834x; 9.6834x over previous
//
#include <hip/hip_runtime.h>
#include <math.h>

typedef __attribute__((ext_vector_type(8))) short short8;
typedef __attribute__((ext_vector_type(4))) float f32x4;
typedef unsigned short ushort_t;

#define B_    1024
#define EPSV  1e-5

__device__ __forceinline__ float sgn(float v){ return (v>0.f)?1.f:((v<0.f)?-1.f:0.f); }
__device__ __forceinline__ ushort_t sgnbits(float v){ return (v>0.f)?(ushort_t)0x3F80:((v<0.f)?(ushort_t)0xBF80:(ushort_t)0); }

// ============ conv1 (binarized in & w) + maxpool2, channel-last out [B][196][64] (pad ch 48..63 = 0) ============
__global__ __launch_bounds__(256) void k_conv1_pool(const float* __restrict__ x,
                                                    const float* __restrict__ w1,
                                                    float* __restrict__ p1){
  int idx = blockIdx.x*256 + threadIdx.x;
  if (idx >= B_*196*64) return;
  int c = idx & 63;
  int p = (idx >> 6) % 196;
  int b = (idx >> 6) / 196;
  if (c >= 48){ p1[idx] = 0.f; return; }
  int y = p/14, xq = p - y*14;
  const float* xb = x + (size_t)b*784;
  float w[9];
#pragma unroll
  for (int k=0;k<9;k++) w[k] = sgn(w1[c*9+k]);
  float sx[4][4];
#pragma unroll
  for (int dy=0; dy<4; dy++){
    int iy = 2*y-1+dy;
#pragma unroll
    for (int dx=0; dx<4; dx++){
      int ix = 2*xq-1+dx;
      sx[dy][dx] = (iy>=0 && iy<28 && ix>=0 && ix<28) ? sgn(xb[iy*28+ix]) : 0.f;
    }
  }
  float best = -1e30f;
#pragma unroll
  for (int py=0;py<2;py++)
#pragma unroll
    for (int px=0;px<2;px++){
      float acc = 0.f;
#pragma unroll
      for (int ky=0;ky<3;ky++)
#pragma unroll
        for (int kx=0;kx<3;kx++)
          acc += sx[py+ky][px+kx]*w[ky*3+kx];
      best = fmaxf(best, acc);
    }
  p1[idx] = best;   // bias b1 cancels in BN
}

// ============ per-channel stats, channel-LAST [rows][C]: one thread per channel column ============
__global__ __launch_bounds__(256) void k_stats_cols(const float* __restrict__ src,
                                                    double* __restrict__ sum,
                                                    double* __restrict__ sumsq,
                                                    int C, long rows){
  int c = blockIdx.x*256 + threadIdx.x;
  if (c >= C) return;
  double a=0.0, a2=0.0;
  for (long r = blockIdx.y; r < rows; r += gridDim.y){
    double v = (double)src[r*(long)C + c];
    a += v; a2 += v*v;
  }
  atomicAdd(&sum[c], a); atomicAdd(&sumsq[c], a2);
}

// ============ per-channel stats, channel-FIRST [B][C][S] ============
__global__ __launch_bounds__(256) void k_stats_cf(const float* __restrict__ src,
                                                  double* __restrict__ sum,
                                                  double* __restrict__ sumsq,
                                                  int Bn, int C, int S){
  int c = blockIdx.x;
  long NS = (long)Bn*S;
  double a=0.0, a2=0.0;
  long stride = (long)gridDim.y*blockDim.x;
  for (long i = (long)blockIdx.y*blockDim.x + threadIdx.x; i < NS; i += stride){
    long b = i / S, s = i - b*S;
    double v = (double)src[((size_t)b*C + c)*S + s];
    a += v; a2 += v*v;
  }
  __shared__ double rs[256], rs2[256];
  rs[threadIdx.x]=a; rs2[threadIdx.x]=a2;
  __syncthreads();
  for (int off=128; off>0; off>>=1){
    if (threadIdx.x < off){ rs[threadIdx.x]+=rs[threadIdx.x+off]; rs2[threadIdx.x]+=rs2[threadIdx.x+off]; }
    __syncthreads();
  }
  if (threadIdx.x==0){ atomicAdd(&sum[c], rs[0]); atomicAdd(&sumsq[c], rs2[0]); }
}

// ============ bn scale/shift ============
__global__ void k_bnparams(const double* __restrict__ sum, const double* __restrict__ sumsq,
                           const float* __restrict__ g, const float* __restrict__ be,
                           float* __restrict__ scale, float* __restrict__ shift,
                           int C, int validC, double invN){
  int c = blockIdx.x*blockDim.x + threadIdx.x;
  if (c >= C) return;
  if (c >= validC){ scale[c]=0.f; shift[c]=0.f; return; }
  double m   = sum[c]*invN;
  double var = sumsq[c]*invN - m*m;
  double s   = (double)g[c] / sqrt(var + EPSV);
  scale[c] = (float)s;
  shift[c] = (float)((double)be[c] - m*s);
}

// ============ bn + sign -> bf16 bits ============
__global__ __launch_bounds__(256) void k_norm_sign(const float* __restrict__ src,
                                                   ushort_t* __restrict__ dst,
                                                   const float* __restrict__ scale,
                                                   const float* __restrict__ shift,
                                                   int C, int S, int total){
  int i = blockIdx.x*256 + threadIdx.x;
  if (i >= total) return;
  int c = (i / S) % C;
  float v = fmaf(src[i], scale[c], shift[c]);
  dst[i] = sgnbits(v);
}

// ============ bn + htanh in place (fp32) ============
__global__ __launch_bounds__(256) void k_norm_htanh(float* __restrict__ buf,
                                                    const float* __restrict__ scale,
                                                    const float* __restrict__ shift,
                                                    int C, int total){
  int i = blockIdx.x*256 + threadIdx.x;
  if (i >= total) return;
  int c = i % C;
  float v = fmaf(buf[i], scale[c], shift[c]);
  buf[i] = fminf(fmaxf(v,-1.f),1.f);
}

// ============ weight prep ============
// w2 [128][48][9] -> w2b bf16 [128][9*64] (k = kk*64+ic, ic padded to 64)
__global__ __launch_bounds__(256) void k_prep_w2(const float* __restrict__ w2, ushort_t* __restrict__ out){
  int idx = blockIdx.x*256 + threadIdx.x;
  if (idx >= 128*576) return;
  int oc = idx / 576, r = idx - oc*576;
  int kk = r >> 6, ic = r & 63;
  out[idx] = (ic < 48) ? sgnbits(w2[oc*432 + ic*9 + kk]) : (ushort_t)0;
}
// w3 [256][128][9] -> w3b bf16 [256][9*128] (k = kk*128+ic)
__global__ __launch_bounds__(256) void k_prep_w3(const float* __restrict__ w3, ushort_t* __restrict__ out){
  int idx = blockIdx.x*256 + threadIdx.x;
  if (idx >= 256*1152) return;
  int oc = idx / 1152, r = idx - oc*1152;
  int kk = r >> 7, ic = r & 127;
  out[idx] = sgnbits(w3[oc*1152 + ic*9 + kk]);
}
// wf1 [2048][12544] -> bf16 sign, same order (4 elems/thread)
__global__ __launch_bounds__(256) void k_prep_wf1(const float* __restrict__ wf1, ushort_t* __restrict__ out){
  int idx = blockIdx.x*256 + threadIdx.x;
  if (idx >= 2048*12544/4) return;
  const float4 v = *reinterpret_cast<const float4*>(&wf1[(size_t)idx*4]);
  ushort4 o;
  o.x = sgnbits(v.x); o.y = sgnbits(v.y); o.z = sgnbits(v.z); o.w = sgnbits(v.w);
  *reinterpret_cast<ushort4*>(&out[(size_t)idx*4]) = o;
}

// ============ conv2 MFMA: a1 [B][196][64]bf16 x w2b -> c2 [B][196][128]f32 ============
__global__ __launch_bounds__(256,2) void k_conv2_mfma(const ushort_t* __restrict__ a1,
                                                      const ushort_t* __restrict__ w2b,
                                                      float* __restrict__ c2){
  __shared__ ushort_t sIn[256*64];     // 32 KB, padded 16x16 spatial, ic 64, chunk-swizzled
  __shared__ ushort_t sW[2][64*40];    // 10 KB dbuf, [oc][k] rows padded 32->40
  int ocb = blockIdx.x*64;
  int b   = blockIdx.y;
  int tid = threadIdx.x;
  // stage input (2048 chunks of 16B)
  {
    const uint4* src4 = reinterpret_cast<const uint4*>(a1 + (size_t)b*196*64);
    for (int i = tid; i < 2048; i += 256){
      int px = i >> 3, ch = i & 7;
      int py = px >> 4, pxx = px & 15;
      uint4 v = make_uint4(0u,0u,0u,0u);
      if (py>=1 && py<=14 && pxx>=1 && pxx<=14)
        v = src4[((py-1)*14 + (pxx-1))*8 + ch];
      *reinterpret_cast<uint4*>(&sIn[px*64 + ((ch ^ (px & 7))<<3)]) = v;
    }
  }
  const uint4* wsrc = reinterpret_cast<const uint4*>(w2b);
  int ocS = ocb + (tid>>2), kcS = tid & 3;
  *reinterpret_cast<uint4*>(&sW[0][(tid>>2)*40 + kcS*8]) = wsrc[(size_t)ocS*72 + kcS];
  __syncthreads();

  int lane = tid & 63, wave = tid >> 6;
  int rA = lane & 15, kch = lane >> 4;
  f32x4 acc[4][4];
#pragma unroll
  for (int t=0;t<4;t++)
#pragma unroll
    for (int n=0;n<4;n++) acc[t][n] = (f32x4){0.f,0.f,0.f,0.f};

  for (int s = 0; s < 18; ++s){
    int cur = s & 1;
    uint4 wpre;
    if (s < 17) wpre = wsrc[(size_t)ocS*72 + (s+1)*4 + kcS];
    short8 bF[4];
#pragma unroll
    for (int n=0;n<4;n++)
      bF[n] = *reinterpret_cast<const short8*>(&sW[cur][(n*16+rA)*40 + kch*8]);
    int kk9 = s >> 1;
    int ky = kk9/3, kx = kk9 - ky*3;
    int chbase = ((s & 1) << 2) + kch;
#pragma unroll
    for (int t=0;t<4;t++){
      int m = t*4 + wave;
      if (m < 13){
        int r = m*16 + rA;
        int rc = r < 196 ? r : 195;
        int y = rc/14, x = rc - y*14;
        int px = (y+ky)*16 + (x+kx);
        short8 aF = *reinterpret_cast<const short8*>(&sIn[px*64 + ((chbase ^ (px&7))<<3)]);
#pragma unroll
        for (int n=0;n<4;n++)
          acc[t][n] = __builtin_amdgcn_mfma_f32_16x16x32_bf16(aF, bF[n], acc[t][n], 0,0,0);
      }
    }
    if (s < 17) *reinterpret_cast<uint4*>(&sW[cur^1][(tid>>2)*40 + kcS*8]) = wpre;
    __syncthreads();
  }
  int colL = lane & 15, rg = lane >> 4;
#pragma unroll
  for (int t=0;t<4;t++){
    int m = t*4 + wave;
    if (m < 13){
#pragma unroll
      for (int n=0;n<4;n++)
#pragma unroll
        for (int j=0;j<4;j++){
          int r = m*16 + rg*4 + j;
          if (r < 196)
            c2[((size_t)b*196 + r)*128 + ocb + n*16 + colL] = acc[t][n][j];
        }
    }
  }
}

// ============ conv3 MFMA + maxpool: a2 [B][196][128]bf16 x w3b -> p3 [B][256][49]f32 (channel-first!) ============
__global__ __launch_bounds__(256,2) void k_conv3_mfma_pool(const ushort_t* __restrict__ a2,
                                                           const ushort_t* __restrict__ w3b,
                                                           float* __restrict__ p3){
  __shared__ ushort_t sIn[256*128];    // 64 KB
  __shared__ ushort_t sW[2][64*40];    // 10 KB
  int ocb = blockIdx.x*64;
  int b   = blockIdx.y;
  int tid = threadIdx.x;
  {
    const uint4* src4 = reinterpret_cast<const uint4*>(a2 + (size_t)b*196*128);
    for (int i = tid; i < 4096; i += 256){
      int px = i >> 4, ch = i & 15;
      int py = px >> 4, pxx = px & 15;
      uint4 v = make_uint4(0u,0u,0u,0u);
      if (py>=1 && py<=14 && pxx>=1 && pxx<=14)
        v = src4[((py-1)*14 + (pxx-1))*16 + ch];
      *reinterpret_cast<uint4*>(&sIn[px*128 + ((ch ^ (px & 15))<<3)]) = v;
    }
  }
  const uint4* wsrc = reinterpret_cast<const uint4*>(w3b);
  int ocS = ocb + (tid>>2), kcS = tid & 3;
  *reinterpret_cast<uint4*>(&sW[0][(tid>>2)*40 + kcS*8]) = wsrc[(size_t)ocS*144 + kcS];
  __syncthreads();

  int lane = tid & 63, wave = tid >> 6;
  int rA = lane & 15, kch = lane >> 4;
  f32x4 acc[4][4];
#pragma unroll
  for (int t=0;t<4;t++)
#pragma unroll
    for (int n=0;n<4;n++) acc[t][n] = (f32x4){0.f,0.f,0.f,0.f};

  for (int s = 0; s < 36; ++s){
    int cur = s & 1;
    uint4 wpre;
    if (s < 35) wpre = wsrc[(size_t)ocS*144 + (s+1)*4 + kcS];
    short8 bF[4];
#pragma unroll
    for (int n=0;n<4;n++)
      bF[n] = *reinterpret_cast<const short8*>(&sW[cur][(n*16+rA)*40 + kch*8]);
    int kk9 = s >> 2;
    int ky = kk9/3, kx = kk9 - ky*3;
    int chbase = ((s & 3) << 2) + kch;
#pragma unroll
    for (int t=0;t<4;t++){
      int m = t*4 + wave;
      if (m < 13){
        int r = m*16 + rA;
        int rc = r < 196 ? r : 195;
        int y = rc/14, x = rc - y*14;
        int px = (y+ky)*16 + (x+kx);
        short8 aF = *reinterpret_cast<const short8*>(&sIn[px*128 + ((chbase ^ (px&15))<<3)]);
#pragma unroll
        for (int n=0;n<4;n++)
          acc[t][n] = __builtin_amdgcn_mfma_f32_16x16x32_bf16(aF, bF[n], acc[t][n], 0,0,0);
      }
    }
    if (s < 35) *reinterpret_cast<uint4*>(&sW[cur^1][(tid>>2)*40 + kcS*8]) = wpre;
    __syncthreads();
  }
  // pool stage: alias fp32 pool buffer [64][212] over sIn (54.3 KB <= 64 KB)
  float* sPool = reinterpret_cast<float*>(sIn);
  int colL = lane & 15, rg = lane >> 4;
#pragma unroll
  for (int t=0;t<4;t++){
    int m = t*4 + wave;
    if (m < 13){
#pragma unroll
      for (int n=0;n<4;n++)
#pragma unroll
        for (int j=0;j<4;j++){
          int r = m*16 + rg*4 + j;
          if (r < 196) sPool[(n*16+colL)*212 + r] = acc[t][n][j];
        }
    }
  }
  __syncthreads();
  for (int i = tid; i < 64*49; i += 256){
    int oc = i/49, cell = i - oc*49;
    int cy = cell/7, cx = cell - cy*7;
    const float* rp = &sPool[oc*212 + cy*28 + cx*2];
    float m0 = fmaxf(rp[0],  rp[1]);
    float m1 = fmaxf(rp[14], rp[15]);
    p3[((size_t)b*256 + ocb + oc)*49 + cell] = fmaxf(m0, m1);   // bias b3 cancels in BN
  }
}

// ============ fc1 MFMA: a3 [1024][12544]bf16 x wf1b [2048][12544]bf16^T -> f1 [1024][2048]f32 ============
__global__ __launch_bounds__(256) void k_fc1_mfma(const ushort_t* __restrict__ A,
                                                  const ushort_t* __restrict__ Bw,
                                                  float* __restrict__ f1){
  __shared__ ushort_t As[2][64*40];    // 10 KB
  __shared__ ushort_t Bs[2][128*40];   // 20 KB
  int bn = blockIdx.x*128, bm = blockIdx.y*64;
  int tid = threadIdx.x;
  int rS = tid >> 2, kcS = tid & 3;
  // stage step 0
  {
    *reinterpret_cast<uint4*>(&As[0][rS*40 + kcS*8]) =
      *reinterpret_cast<const uint4*>(&A[(size_t)(bm+rS)*12544 + kcS*8]);
    *reinterpret_cast<uint4*>(&Bs[0][rS*40 + kcS*8]) =
      *reinterpret_cast<const uint4*>(&Bw[(size_t)(bn+rS)*12544 + kcS*8]);
    *reinterpret_cast<uint4*>(&Bs[0][(64+rS)*40 + kcS*8]) =
      *reinterpret_cast<const uint4*>(&Bw[(size_t)(bn+64+rS)*12544 + kcS*8]);
  }
  __syncthreads();
  int lane = tid & 63, wave = tid >> 6;
  int rA = lane & 15, kch = lane >> 4;
  int mtb = (wave & 1)*2, ntb = (wave >> 1)*4;
  f32x4 acc[2][4];
#pragma unroll
  for (int i=0;i<2;i++)
#pragma unroll
    for (int n=0;n<4;n++) acc[i][n] = (f32x4){0.f,0.f,0.f,0.f};

  for (int s = 0; s < 392; ++s){
    int cur = s & 1;
    uint4 pa, pb0, pb1;
    if (s < 391){
      size_t k0 = (size_t)(s+1)*32 + kcS*8;
      pa  = *reinterpret_cast<const uint4*>(&A [(size_t)(bm+rS)*12544 + k0]);
      pb0 = *reinterpret_cast<const uint4*>(&Bw[(size_t)(bn+rS)*12544 + k0]);
      pb1 = *reinterpret_cast<const uint4*>(&Bw[(size_t)(bn+64+rS)*12544 + k0]);
    }
    short8 aF[2], bF[4];
#pragma unroll
    for (int i=0;i<2;i++)
      aF[i] = *reinterpret_cast<const short8*>(&As[cur][((mtb+i)*16+rA)*40 + kch*8]);
#pragma unroll
    for (int n=0;n<4;n++)
      bF[n] = *reinterpret_cast<const short8*>(&Bs[cur][((ntb+n)*16+rA)*40 + kch*8]);
#pragma unroll
    for (int i=0;i<2;i++)
#pragma unroll
      for (int n=0;n<4;n++)
        acc[i][n] = __builtin_amdgcn_mfma_f32_16x16x32_bf16(aF[i], bF[n], acc[i][n], 0,0,0);
    if (s < 391){
      *reinterpret_cast<uint4*>(&As[cur^1][rS*40 + kcS*8]) = pa;
      *reinterpret_cast<uint4*>(&Bs[cur^1][rS*40 + kcS*8]) = pb0;
      *reinterpret_cast<uint4*>(&Bs[cur^1][(64+rS)*40 + kcS*8]) = pb1;
    }
    __syncthreads();
  }
  int colL = lane & 15, rg = lane >> 4;
#pragma unroll
  for (int i=0;i<2;i++)
#pragma unroll
    for (int n=0;n<4;n++)
#pragma unroll
      for (int j=0;j<4;j++){
        int r = bm + (mtb+i)*16 + rg*4 + j;
        int col = bn + (ntb+n)*16 + colL;
        f1[(size_t)r*2048 + col] = acc[i][n][j];   // bias bf1 cancels in BN
      }
}

// ============ fc2 + log_softmax ============
__global__ __launch_bounds__(256) void k_fc2_lsm(const float* __restrict__ h,
                                                 const float* __restrict__ W,
                                                 const float* __restrict__ bias,
                                                 float* __restrict__ out){
  int b = blockIdx.x;
  const float* hb = h + (size_t)b*2048;
  float acc[10];
#pragma unroll
  for (int o=0;o<10;o++) acc[o]=0.f;
  for (int k=threadIdx.x; k<2048; k+=256){
    float v = hb[k];
#pragma unroll
    for (int o=0;o<10;o++) acc[o] += v*W[o*2048+k];
  }
  __shared__ float red[4][10];
  int wv = threadIdx.x>>6, lanev = threadIdx.x&63;
#pragma unroll
  for (int o=0;o<10;o++){
    float r = acc[o];
    for (int off=32; off>0; off>>=1) r += __shfl_down(r, off);
    if (lanev==0) red[wv][o]=r;
  }
  __syncthreads();
  if (threadIdx.x==0){
    float lg[10], mx=-1e30f;
#pragma unroll
    for (int o=0;o<10;o++){ lg[o]=red[0][o]+red[1][o]+red[2][o]+red[3][o]+bias[o]; mx=fmaxf(mx,lg[o]); }
    float se=0.f;
#pragma unroll
    for (int o=0;o<10;o++) se += expf(lg[o]-mx);
    float lse = mx + logf(se);
#pragma unroll
    for (int o=0;o<10;o++) out[(size_t)b*10+o] = lg[o]-lse;
  }
}

// ================= launch =================
extern "C" void kernel_launch(void* const* d_in, const int* in_sizes, int n_in,
                              void* d_out, int out_size, void* d_ws, size_t ws_size,
                              hipStream_t stream){
  (void)in_sizes; (void)n_in; (void)out_size; (void)ws_size;
  const float* x   = (const float*)d_in[0];
  const float* w1  = (const float*)d_in[1];
  const float* g1  = (const float*)d_in[3];
  const float* be1 = (const float*)d_in[4];
  const float* w2  = (const float*)d_in[5];
  const float* g2  = (const float*)d_in[7];
  const float* be2 = (const float*)d_in[8];
  const float* w3  = (const float*)d_in[9];
  const float* g3  = (const float*)d_in[11];
  const float* be3 = (const float*)d_in[12];
  const float* wf1 = (const float*)d_in[13];
  const float* g4  = (const float*)d_in[15];
  const float* be4 = (const float*)d_in[16];
  const float* wf2 = (const float*)d_in[17];
  const float* bf2 = (const float*)d_in[18];
  float* out = (float*)d_out;

  char* W = (char*)d_ws;
  double* sum   = (double*)W;                 // 2048 dbl
  double* sumsq = sum + 2048;                 // ends 32768
  float*  scale = (float*)(W + 32768);
  float*  shift = scale + 2048;               // ends 49152
  // buffer plan (bytes from base, aggressive reuse; peak 189.0 MB < round-0's 192.7 MB):
  float*    p1   = (float*)   (W + 65536);          // [B][196][64] f32   (dead after norm1)
  float*    c2   = (float*)   (W + 65536);          // [B][196][128] f32  (same region; p1 dead)
  float*    p3   = (float*)   (W + 65536);          // [B][256][49] f32   (c2 dead)
  ushort_t* a3   = (ushort_t*)(W + 51445760);       // [B][256][49] bf16
  ushort_t* wf1b = (ushort_t*)(W + 77135872);       // [2048][12544] bf16 (over dead c2-tail/a1)
  ushort_t* a1   = (ushort_t*)(W + 102825984);      // [B][196][64] bf16  (dead after conv2)
  ushort_t* w2b  = (ushort_t*)(W + 128516096);      // [128][576] bf16
  ushort_t* a2   = (ushort_t*)(W + 128663552);      // [B][196][128] bf16
  ushort_t* w3b  = (ushort_t*)(W + 180043776);      // [256][1152] bf16
  float*    f1   = (float*)   (W + 180633600);      // [1024][2048] f32 -> ends 189,022,208

  // ---- layer 1 ----
  k_conv1_pool<<<50176, 256, 0, stream>>>(x, w1, p1);
  hipMemsetAsync(sum, 0, 32768, stream);
  k_stats_cols<<<dim3(1,512), 256, 0, stream>>>(p1, sum, sumsq, 64, 200704L);
  k_bnparams<<<1, 256, 0, stream>>>(sum, sumsq, g1, be1, scale, shift, 64, 48, 1.0/200704.0);
  k_norm_sign<<<50176, 256, 0, stream>>>(p1, a1, scale, shift, 64, 1, 12845056);
  // ---- layer 2 ----
  k_prep_w2<<<288, 256, 0, stream>>>(w2, w2b);
  k_conv2_mfma<<<dim3(2, B_), 256, 0, stream>>>(a1, w2b, c2);
  hipMemsetAsync(sum, 0, 32768, stream);
  k_stats_cols<<<dim3(1,512), 256, 0, stream>>>(c2, sum, sumsq, 128, 200704L);
  k_bnparams<<<1, 256, 0, stream>>>(sum, sumsq, g2, be2, scale, shift, 128, 128, 1.0/200704.0);
  k_norm_sign<<<100352, 256, 0, stream>>>(c2, a2, scale, shift, 128, 1, 25690112);
  k_prep_wf1<<<25088, 256, 0, stream>>>(wf1, wf1b);   // after norm2: region overlapped c2/a1
  // ---- layer 3 ----
  k_prep_w3<<<1152, 256, 0, stream>>>(w3, w3b);
  k_conv3_mfma_pool<<<dim3(4, B_), 256, 0, stream>>>(a2, w3b, p3);
  hipMemsetAsync(sum, 0, 32768, stream);
  k_stats_cf<<<dim3(256,16), 256, 0, stream>>>(p3, sum, sumsq, B_, 256, 49);
  k_bnparams<<<1, 256, 0, stream>>>(sum, sumsq, g3, be3, scale, shift, 256, 256, 1.0/50176.0);
  k_norm_sign<<<50176, 256, 0, stream>>>(p3, a3, scale, shift, 256, 49, 12845056);
  // ---- fc1 ----
  k_fc1_mfma<<<dim3(16,16), 256, 0, stream>>>(a3, wf1b, f1);
  hipMemsetAsync(sum, 0, 32768, stream);
  k_stats_cols<<<dim3(8,64), 256, 0, stream>>>(f1, sum, sumsq, 2048, 1024L);
  k_bnparams<<<8, 256, 0, stream>>>(sum, sumsq, g4, be4, scale, shift, 2048, 2048, 1.0/1024.0);
  k_norm_htanh<<<8192, 256, 0, stream>>>(f1, scale, shift, 2048, 2097152);
  // ---- fc2 + log_softmax ----
  k_fc2_lsm<<<B_, 256, 0, stream>>>(f1, wf2, bf2, out);
}

// Round 5
// 1077.314 us; speedup vs baseline: 9.7409x; 1.0059x over previous
//
#include <hip/hip_runtime.h>
#include <math.h>

typedef __attribute__((ext_vector_type(8))) short short8;
typedef __attribute__((ext_vector_type(4))) float f32x4;
typedef unsigned short ushort_t;

#define B_    1024
#define EPSV  1e-5

__device__ __forceinline__ float sgn(float v){ return (v>0.f)?1.f:((v<0.f)?-1.f:0.f); }
__device__ __forceinline__ ushort_t sgnbits(float v){ return (v>0.f)?(ushort_t)0x3F80:((v<0.f)?(ushort_t)0xBF80:(ushort_t)0); }

// conflict-free weight-tile byte offset: row o, 16B chunk c (0..3), 64B rows. Bijective.
#define SWZW(o,c) ( ((o)<<6) ^ ((((c) ^ ((o)&7)) & 7) << 4) )
// 128B rows (fc1): chunk c 0..7, disjoint bits -> bijective
#define SWZF(o,c) ( ((o)<<7) + ((((c) ^ ((o)&7)) & 7) << 4) )

// ============ conv1 (binarized in & w) + maxpool2 -> [B][196][64] f32 (ch 48..63 = 0) ============
__global__ __launch_bounds__(256) void k_conv1_pool(const float* __restrict__ x,
                                                    const float* __restrict__ w1,
                                                    float* __restrict__ p1){
  int idx = blockIdx.x*256 + threadIdx.x;
  if (idx >= B_*196*64) return;
  int c = idx & 63;
  int p = (idx >> 6) % 196;
  int b = (idx >> 6) / 196;
  if (c >= 48){ p1[idx] = 0.f; return; }
  int y = p/14, xq = p - y*14;
  const float* xb = x + (size_t)b*784;
  float w[9];
#pragma unroll
  for (int k=0;k<9;k++) w[k] = sgn(w1[c*9+k]);
  float sx[4][4];
#pragma unroll
  for (int dy=0; dy<4; dy++){
    int iy = 2*y-1+dy;
#pragma unroll
    for (int dx=0; dx<4; dx++){
      int ix = 2*xq-1+dx;
      sx[dy][dx] = (iy>=0 && iy<28 && ix>=0 && ix<28) ? sgn(xb[iy*28+ix]) : 0.f;
    }
  }
  float best = -1e30f;
#pragma unroll
  for (int py=0;py<2;py++)
#pragma unroll
    for (int px=0;px<2;px++){
      float acc = 0.f;
#pragma unroll
      for (int ky=0;ky<3;ky++)
#pragma unroll
        for (int kx=0;kx<3;kx++)
          acc += sx[py+ky][px+kx]*w[ky*3+kx];
      best = fmaxf(best, acc);
    }
  p1[idx] = best;   // bias b1 cancels in BN
}

// ============ layer-1 stats: channel-last [rows][64], LDS-reduced, f64 atomics ============
__global__ __launch_bounds__(256) void k_stats_cl64(const float* __restrict__ src,
                                                    double* __restrict__ sum,
                                                    double* __restrict__ sumsq,
                                                    long rows){
  int c = threadIdx.x & 63, sl = threadIdx.x >> 6;
  double a=0.0, q=0.0;
  long stride = (long)gridDim.y*4;
  for (long r = (long)blockIdx.y*4 + sl; r < rows; r += stride){
    double v = (double)src[r*64 + c];
    a += v; q += v*v;
  }
  __shared__ double sA[256], sQd[256];
  sA[threadIdx.x]=a; sQd[threadIdx.x]=q;
  __syncthreads();
  if (threadIdx.x < 64){
    a = sA[threadIdx.x] + sA[threadIdx.x+64] + sA[threadIdx.x+128] + sA[threadIdx.x+192];
    q = sQd[threadIdx.x] + sQd[threadIdx.x+64] + sQd[threadIdx.x+128] + sQd[threadIdx.x+192];
    atomicAdd(&sum[c], a); atomicAdd(&sumsq[c], q);
  }
}

// ============ reduce f32 partial arrays [nPart][C] -> f64 sum/sumsq ============
__global__ __launch_bounds__(256) void k_reduce_stats(const float* __restrict__ pS,
                                                      const float* __restrict__ pQ,
                                                      double* __restrict__ sum,
                                                      double* __restrict__ sumsq,
                                                      int C, int nPart){
  int c = blockIdx.x*256 + threadIdx.x;
  if (c >= C) return;
  int per = (nPart + gridDim.y - 1)/gridDim.y;
  int p0 = blockIdx.y*per, p1 = p0+per; if (p1 > nPart) p1 = nPart;
  double a=0.0, q=0.0;
  for (int p = p0; p < p1; ++p){
    a += (double)pS[(size_t)p*C + c];
    q += (double)pQ[(size_t)p*C + c];
  }
  atomicAdd(&sum[c], a); atomicAdd(&sumsq[c], q);
}

// ============ bn scale/shift ============
__global__ void k_bnparams(const double* __restrict__ sum, const double* __restrict__ sumsq,
                           const float* __restrict__ g, const float* __restrict__ be,
                           float* __restrict__ scale, float* __restrict__ shift,
                           int C, int validC, double invN){
  int c = blockIdx.x*blockDim.x + threadIdx.x;
  if (c >= C) return;
  if (c >= validC){ scale[c]=0.f; shift[c]=0.f; return; }
  double m   = sum[c]*invN;
  double var = sumsq[c]*invN - m*m;
  double s   = (double)g[c] / sqrt(var + EPSV);
  scale[c] = (float)s;
  shift[c] = (float)((double)be[c] - m*s);
}

// ============ bn + sign -> bf16 bits ============
__global__ __launch_bounds__(256) void k_norm_sign(const float* __restrict__ src,
                                                   ushort_t* __restrict__ dst,
                                                   const float* __restrict__ scale,
                                                   const float* __restrict__ shift,
                                                   int C, int S, int total){
  int i = blockIdx.x*256 + threadIdx.x;
  if (i >= total) return;
  int c = (i / S) % C;
  float v = fmaf(src[i], scale[c], shift[c]);
  dst[i] = sgnbits(v);
}

// ============ bn + htanh in place (fp32) ============
__global__ __launch_bounds__(256) void k_norm_htanh(float* __restrict__ buf,
                                                    const float* __restrict__ scale,
                                                    const float* __restrict__ shift,
                                                    int C, int total){
  int i = blockIdx.x*256 + threadIdx.x;
  if (i >= total) return;
  int c = i % C;
  float v = fmaf(buf[i], scale[c], shift[c]);
  buf[i] = fminf(fmaxf(v,-1.f),1.f);
}

// ============ weight prep ============
__global__ __launch_bounds__(256) void k_prep_w2(const float* __restrict__ w2, ushort_t* __restrict__ out){
  int idx = blockIdx.x*256 + threadIdx.x;
  if (idx >= 128*576) return;
  int oc = idx / 576, r = idx - oc*576;
  int kk = r >> 6, ic = r & 63;
  out[idx] = (ic < 48) ? sgnbits(w2[oc*432 + ic*9 + kk]) : (ushort_t)0;
}
__global__ __launch_bounds__(256) void k_prep_w3(const float* __restrict__ w3, ushort_t* __restrict__ out){
  int idx = blockIdx.x*256 + threadIdx.x;
  if (idx >= 256*1152) return;
  int oc = idx / 1152, r = idx - oc*1152;
  int kk = r >> 7, ic = r & 127;
  out[idx] = sgnbits(w3[oc*1152 + ic*9 + kk]);
}
__global__ __launch_bounds__(256) void k_prep_wf1(const float* __restrict__ wf1, ushort_t* __restrict__ out){
  int idx = blockIdx.x*256 + threadIdx.x;
  if (idx >= 2048*12544/4) return;
  const float4 v = *reinterpret_cast<const float4*>(&wf1[(size_t)idx*4]);
  ushort4 o;
  o.x = sgnbits(v.x); o.y = sgnbits(v.y); o.z = sgnbits(v.z); o.w = sgnbits(v.w);
  *reinterpret_cast<ushort4*>(&out[(size_t)idx*4]) = o;
}

// ============ conv2 MFMA: a1 [B][196][64]bf16 x w2b[128][576] -> c2 [B][196][128]f32 + stats ============
__global__ __launch_bounds__(256,2) void k_conv2_mfma(const ushort_t* __restrict__ a1,
                                                      const ushort_t* __restrict__ w2b,
                                                      float* __restrict__ c2,
                                                      float* __restrict__ pS,
                                                      float* __restrict__ pQ){
  __shared__ ushort_t sIn[256*64];     // 32 KB
  __shared__ char     sWb[2][8192];    // 16 KB dbuf, SWZW layout
  __shared__ float    sRS[128], sRQ[128];
  int b = blockIdx.x, tid = threadIdx.x;
  {
    const uint4* src4 = reinterpret_cast<const uint4*>(a1 + (size_t)b*196*64);
    for (int i = tid; i < 2048; i += 256){
      int px = i >> 3, ch = i & 7;
      int py = px >> 4, pxx = px & 15;
      uint4 v = make_uint4(0u,0u,0u,0u);
      if (py>=1 && py<=14 && pxx>=1 && pxx<=14)
        v = src4[((py-1)*14 + (pxx-1))*8 + ch];
      *reinterpret_cast<uint4*>(&sIn[px*64 + ((ch ^ (px & 7))<<3)]) = v;
    }
  }
  if (tid < 128){ sRS[tid]=0.f; sRQ[tid]=0.f; }
  const uint4* gW = reinterpret_cast<const uint4*>(w2b);  // row = 72 uint4
  int cS = tid & 3, rS = (tid >> 2)*2;
  {
    uint4 v0 = gW[(size_t)rS*72 + cS];
    uint4 v1 = gW[(size_t)(rS+1)*72 + cS];
    *reinterpret_cast<uint4*>(&sWb[0][SWZW(rS,  cS)]) = v0;
    *reinterpret_cast<uint4*>(&sWb[0][SWZW(rS+1,cS)]) = v1;
  }
  __syncthreads();
  int lane = tid & 63, wave = tid >> 6;
  int rA = lane & 15, kch = lane >> 4;
  f32x4 acc[4][8];
#pragma unroll
  for (int t=0;t<4;t++)
#pragma unroll
    for (int n=0;n<8;n++) acc[t][n] = (f32x4){0.f,0.f,0.f,0.f};

  for (int s = 0; s < 18; ++s){
    int cur = s & 1;
    uint4 w0, w1;
    if (s < 17){
      w0 = gW[(size_t)rS*72 + (s+1)*4 + cS];
      w1 = gW[(size_t)(rS+1)*72 + (s+1)*4 + cS];
    }
    short8 bF[8];
#pragma unroll
    for (int n=0;n<8;n++){
      int o = n*16 + rA;
      bF[n] = *reinterpret_cast<const short8*>(&sWb[cur][SWZW(o, kch)]);
    }
    int kk9 = s >> 1;
    int ky = kk9/3, kx = kk9 - ky*3;
    int chbase = ((s & 1) << 2) + kch;
#pragma unroll
    for (int t=0;t<4;t++){
      int m = t*4 + wave;
      if (m < 13){
        int r = m*16 + rA;
        int rc = r < 196 ? r : 195;
        int y = rc/14, x = rc - y*14;
        int px = (y+ky)*16 + (x+kx);
        short8 aF = *reinterpret_cast<const short8*>(&sIn[px*64 + ((chbase ^ (px&7))<<3)]);
#pragma unroll
        for (int n=0;n<8;n++)
          acc[t][n] = __builtin_amdgcn_mfma_f32_16x16x32_bf16(aF, bF[n], acc[t][n], 0,0,0);
      }
    }
    if (s < 17){
      *reinterpret_cast<uint4*>(&sWb[cur^1][SWZW(rS,  cS)]) = w0;
      *reinterpret_cast<uint4*>(&sWb[cur^1][SWZW(rS+1,cS)]) = w1;
    }
    __syncthreads();
  }
  // epilogue: write c2 + per-column stats (exact in f32: even ints; squares mult of 4, < 2^26)
  int colL = lane & 15, rg = lane >> 4;
  float csum[8], csq[8];
#pragma unroll
  for (int n=0;n<8;n++){ csum[n]=0.f; csq[n]=0.f; }
#pragma unroll
  for (int t=0;t<4;t++){
    int m = t*4 + wave;
    if (m < 13){
#pragma unroll
      for (int n=0;n<8;n++)
#pragma unroll
        for (int j=0;j<4;j++){
          int r = m*16 + rg*4 + j;
          if (r < 196){
            float v = acc[t][n][j];
            c2[((size_t)b*196 + r)*128 + n*16 + colL] = v;
            csum[n] += v; csq[n] += v*v;
          }
        }
    }
  }
#pragma unroll
  for (int n=0;n<8;n++){
    float a = csum[n], q = csq[n];
    a += __shfl_down(a,32); a += __shfl_down(a,16);
    q += __shfl_down(q,32); q += __shfl_down(q,16);
    if (rg == 0){
      atomicAdd(&sRS[n*16+colL], a);
      atomicAdd(&sRQ[n*16+colL], q);
    }
  }
  __syncthreads();
  if (tid < 128){
    pS[(size_t)b*128 + tid] = sRS[tid];
    pQ[(size_t)b*128 + tid] = sRQ[tid];
  }
}

// ============ conv3 MFMA + maxpool: a2 [B][196][128]bf16 x w3b[256][1152] -> p3 [B][256][49]f32 + stats ============
// ic split into two 64-ch halves (32 KB sIn each, one mid-kernel re-stage) -> room for weight dbuf.
__global__ __launch_bounds__(256,2) void k_conv3_mfma_pool(const ushort_t* __restrict__ a2,
                                                           const ushort_t* __restrict__ w3b,
                                                           float* __restrict__ p3,
                                                           float* __restrict__ pS,
                                                           float* __restrict__ pQ){
  __shared__ ushort_t sIn[256*64];     // 32 KB (pool buffer aliases this)
  __shared__ char     sWb[2][8192];    // 16 KB dbuf
  __shared__ float    sS[32], sQ[32];
  int ocb = blockIdx.x*128;
  int b   = blockIdx.y;
  int tid = threadIdx.x;
  const uint4* src4 = reinterpret_cast<const uint4*>(a2 + (size_t)b*196*128);  // 16 uint4/px
  // stage ic-half 0
  for (int i = tid; i < 2048; i += 256){
    int px = i >> 3, ch = i & 7;
    int py = px >> 4, pxx = px & 15;
    uint4 v = make_uint4(0u,0u,0u,0u);
    if (py>=1 && py<=14 && pxx>=1 && pxx<=14)
      v = src4[((py-1)*14 + (pxx-1))*16 + ch];
    *reinterpret_cast<uint4*>(&sIn[px*64 + ((ch ^ (px & 7))<<3)]) = v;
  }
  const uint4* gW = reinterpret_cast<const uint4*>(w3b);  // row = 144 uint4
  int cS = tid & 3, rS = (tid >> 2)*2;
  {
    uint4 v0 = gW[(size_t)(ocb+rS)*144 + cS];
    uint4 v1 = gW[(size_t)(ocb+rS+1)*144 + cS];
    *reinterpret_cast<uint4*>(&sWb[0][SWZW(rS,  cS)]) = v0;
    *reinterpret_cast<uint4*>(&sWb[0][SWZW(rS+1,cS)]) = v1;
  }
  __syncthreads();
  int lane = tid & 63, wave = tid >> 6;
  int rA = lane & 15, kch = lane >> 4;
  f32x4 acc[4][8];
#pragma unroll
  for (int t=0;t<4;t++)
#pragma unroll
    for (int n=0;n<8;n++) acc[t][n] = (f32x4){0.f,0.f,0.f,0.f};

  // s: 0..35. h = s>=18 (ic half), sloc = s-18h; kk = sloc>>1, sub = sloc&1.
  // weight uint4 offset for step s: kk*16 + h*8 + sub*4
  for (int s = 0; s < 36; ++s){
    int cur = s & 1;
    uint4 w0, w1;
    if (s < 35){
      int s1 = s+1; int h1 = (s1 >= 18); int sl1 = s1 - h1*18;
      int wofs = (sl1>>1)*16 + h1*8 + (sl1&1)*4;
      w0 = gW[(size_t)(ocb+rS)*144 + wofs + cS];
      w1 = gW[(size_t)(ocb+rS+1)*144 + wofs + cS];
    }
    short8 bF[8];
#pragma unroll
    for (int n=0;n<8;n++){
      int o = n*16 + rA;
      bF[n] = *reinterpret_cast<const short8*>(&sWb[cur][SWZW(o, kch)]);
    }
    int h = (s >= 18); int sloc = s - h*18;
    int kk9 = sloc >> 1;
    int ky = kk9/3, kx = kk9 - ky*3;
    int chbase = ((sloc & 1) << 2) + kch;      // 8-elem chunk within 64-ic half
#pragma unroll
    for (int t=0;t<4;t++){
      int m = t*4 + wave;
      if (m < 13){
        int r = m*16 + rA;
        int rc = r < 196 ? r : 195;
        int y = rc/14, x = rc - y*14;
        int px = (y+ky)*16 + (x+kx);
        short8 aF = *reinterpret_cast<const short8*>(&sIn[px*64 + ((chbase ^ (px&7))<<3)]);
#pragma unroll
        for (int n=0;n<8;n++)
          acc[t][n] = __builtin_amdgcn_mfma_f32_16x16x32_bf16(aF, bF[n], acc[t][n], 0,0,0);
      }
    }
    if (s < 35){
      *reinterpret_cast<uint4*>(&sWb[cur^1][SWZW(rS,  cS)]) = w0;
      *reinterpret_cast<uint4*>(&sWb[cur^1][SWZW(rS+1,cS)]) = w1;
    }
    if (s == 17){
      __syncthreads();           // all reads of sIn half-0 done; weight writes drained
      for (int i = tid; i < 2048; i += 256){
        int px = i >> 3, ch = i & 7;
        int py = px >> 4, pxx = px & 15;
        uint4 v = make_uint4(0u,0u,0u,0u);
        if (py>=1 && py<=14 && pxx>=1 && pxx<=14)
          v = src4[((py-1)*14 + (pxx-1))*16 + 8 + ch];
        *reinterpret_cast<uint4*>(&sIn[px*64 + ((ch ^ (px & 7))<<3)]) = v;
      }
      __syncthreads();
    } else {
      __syncthreads();
    }
  }
  // pool + stats in four 32-oc passes; sPool aliases sIn: [32][197] f32 = 25.2 KB
  float* sPool = reinterpret_cast<float*>(sIn);
  int colL = lane & 15, rg = lane >> 4;
  for (int q = 0; q < 4; ++q){
    __syncthreads();
#pragma unroll
    for (int t=0;t<4;t++){
      int m = t*4 + wave;
      if (m < 13){
#pragma unroll
        for (int nl=0;nl<2;nl++){
          int n = q*2 + nl;
#pragma unroll
          for (int j=0;j<4;j++){
            int r = m*16 + rg*4 + j;
            if (r < 196) sPool[(nl*16+colL)*197 + r] = acc[t][n][j];
          }
        }
      }
    }
    if (tid < 32){ sS[tid]=0.f; sQ[tid]=0.f; }
    __syncthreads();
    for (int i = tid; i < 32*49; i += 256){
      int oc = i/49, cell = i - oc*49;
      int cy = cell/7, cx = cell - cy*7;
      const float* rp = &sPool[oc*197 + cy*28 + cx*2];
      float v = fmaxf(fmaxf(rp[0],rp[1]), fmaxf(rp[14],rp[15]));
      p3[((size_t)b*256 + ocb + q*32 + oc)*49 + cell] = v;   // bias b3 cancels in BN
      atomicAdd(&sS[oc], v); atomicAdd(&sQ[oc], v*v);
    }
    __syncthreads();
    if (tid < 32){
      pS[(size_t)b*256 + ocb + q*32 + tid] = sS[tid];
      pQ[(size_t)b*256 + ocb + q*32 + tid] = sQ[tid];
    }
  }
}

// ============ fc1 MFMA: a3 [1024][12544] x wf1b [2048][12544]^T -> f1 [1024][2048] + col stats ============
// 64m x 128n tiles, 16x16 panel grid (256 blocks). id&15 = m-panel (XCD keeps A-panels L2-resident).
__global__ __launch_bounds__(256,2) void k_fc1_mfma(const ushort_t* __restrict__ A,
                                                    const ushort_t* __restrict__ Bw,
                                                    float* __restrict__ f1,
                                                    float* __restrict__ pS,
                                                    float* __restrict__ pQ){
  __shared__ char As[2][8192];    // [64 rows][128B], SWZF
  __shared__ char Bs[2][16384];   // [128 rows][128B], SWZF
  __shared__ float sCS[128], sCQ[128];
  int id = blockIdx.x;
  int bm = (id & 15) << 6, bn = (id >> 4) << 7;
  int tid = threadIdx.x;
  int cS = tid & 7;
  int rS = tid >> 3;              // 0..31
  const uint4* gA = reinterpret_cast<const uint4*>(A);   // row = 1568 uint4
  const uint4* gB = reinterpret_cast<const uint4*>(Bw);
  {
    *reinterpret_cast<uint4*>(&As[0][SWZF(rS,   cS)]) = gA[(size_t)(bm+rS   )*1568 + cS];
    *reinterpret_cast<uint4*>(&As[0][SWZF(rS+32,cS)]) = gA[(size_t)(bm+rS+32)*1568 + cS];
#pragma unroll
    for (int j=0;j<4;j++)
      *reinterpret_cast<uint4*>(&Bs[0][SWZF(rS+j*32,cS)]) = gB[(size_t)(bn+rS+j*32)*1568 + cS];
  }
  if (tid < 128){ sCS[tid]=0.f; sCQ[tid]=0.f; }
  __syncthreads();
  int lane = tid & 63, wave = tid >> 6;
  int rA = lane & 15, kch = lane >> 4;
  int wm = wave & 1, wn = wave >> 1;
  f32x4 acc[2][4];
#pragma unroll
  for (int i=0;i<2;i++)
#pragma unroll
    for (int n=0;n<4;n++) acc[i][n] = (f32x4){0.f,0.f,0.f,0.f};

  for (int s = 0; s < 196; ++s){
    int cur = s & 1;
    uint4 pa0, pa1, pb[4];
    if (s < 195){
      size_t k0 = (size_t)(s+1)*8 + cS;
      pa0 = gA[(size_t)(bm+rS   )*1568 + k0];
      pa1 = gA[(size_t)(bm+rS+32)*1568 + k0];
#pragma unroll
      for (int j=0;j<4;j++)
        pb[j] = gB[(size_t)(bn+rS+j*32)*1568 + k0];
    }
#pragma unroll
    for (int u = 0; u < 2; ++u){
      short8 aF[2], bF[4];
#pragma unroll
      for (int i=0;i<2;i++){
        int ro = wm*32 + i*16 + rA;
        aF[i] = *reinterpret_cast<const short8*>(&As[cur][SWZF(ro, u*4+kch)]);
      }
#pragma unroll
      for (int n=0;n<4;n++){
        int co = wn*64 + n*16 + rA;
        bF[n] = *reinterpret_cast<const short8*>(&Bs[cur][SWZF(co, u*4+kch)]);
      }
#pragma unroll
      for (int i=0;i<2;i++)
#pragma unroll
        for (int n=0;n<4;n++)
          acc[i][n] = __builtin_amdgcn_mfma_f32_16x16x32_bf16(aF[i], bF[n], acc[i][n], 0,0,0);
    }
    if (s < 195){
      *reinterpret_cast<uint4*>(&As[cur^1][SWZF(rS,   cS)]) = pa0;
      *reinterpret_cast<uint4*>(&As[cur^1][SWZF(rS+32,cS)]) = pa1;
#pragma unroll
      for (int j=0;j<4;j++)
        *reinterpret_cast<uint4*>(&Bs[cur^1][SWZF(rS+j*32,cS)]) = pb[j];
    }
    __syncthreads();
  }
  // epilogue: f1 write (bias bf1 cancels in bn1d) + per-column partials
  int colL = lane & 15, rg = lane >> 4;
#pragma unroll
  for (int n=0;n<4;n++){
    float ls = 0.f, lq = 0.f;
#pragma unroll
    for (int i=0;i<2;i++)
#pragma unroll
      for (int j=0;j<4;j++){
        int r = bm + wm*32 + i*16 + rg*4 + j;
        float v = acc[i][n][j];
        f1[(size_t)r*2048 + bn + wn*64 + n*16 + colL] = v;
        ls += v; lq += v*v;
      }
    ls += __shfl_down(ls,32); ls += __shfl_down(ls,16);
    lq += __shfl_down(lq,32); lq += __shfl_down(lq,16);
    if (rg == 0){
      atomicAdd(&sCS[wn*64 + n*16 + colL], ls);
      atomicAdd(&sCQ[wn*64 + n*16 + colL], lq);
    }
  }
  __syncthreads();
  if (tid < 128){
    pS[(size_t)(id&15)*2048 + bn + tid] = sCS[tid];
    pQ[(size_t)(id&15)*2048 + bn + tid] = sCQ[tid];
  }
}

// ============ fc2 + log_softmax ============
__global__ __launch_bounds__(256) void k_fc2_lsm(const float* __restrict__ h,
                                                 const float* __restrict__ W,
                                                 const float* __restrict__ bias,
                                                 float* __restrict__ out){
  int b = blockIdx.x;
  const float* hb = h + (size_t)b*2048;
  float acc[10];
#pragma unroll
  for (int o=0;o<10;o++) acc[o]=0.f;
  for (int k=threadIdx.x; k<2048; k+=256){
    float v = hb[k];
#pragma unroll
    for (int o=0;o<10;o++) acc[o] += v*W[o*2048+k];
  }
  __shared__ float red[4][10];
  int wv = threadIdx.x>>6, lanev = threadIdx.x&63;
#pragma unroll
  for (int o=0;o<10;o++){
    float r = acc[o];
    for (int off=32; off>0; off>>=1) r += __shfl_down(r, off);
    if (lanev==0) red[wv][o]=r;
  }
  __syncthreads();
  if (threadIdx.x==0){
    float lg[10], mx=-1e30f;
#pragma unroll
    for (int o=0;o<10;o++){ lg[o]=red[0][o]+red[1][o]+red[2][o]+red[3][o]+bias[o]; mx=fmaxf(mx,lg[o]); }
    float se=0.f;
#pragma unroll
    for (int o=0;o<10;o++) se += expf(lg[o]-mx);
    float lse = mx + logf(se);
#pragma unroll
    for (int o=0;o<10;o++) out[(size_t)b*10+o] = lg[o]-lse;
  }
}

// ================= launch =================
extern "C" void kernel_launch(void* const* d_in, const int* in_sizes, int n_in,
                              void* d_out, int out_size, void* d_ws, size_t ws_size,
                              hipStream_t stream){
  (void)in_sizes; (void)n_in; (void)out_size; (void)ws_size;
  const float* x   = (const float*)d_in[0];
  const float* w1  = (const float*)d_in[1];
  const float* g1  = (const float*)d_in[3];
  const float* be1 = (const float*)d_in[4];
  const float* w2  = (const float*)d_in[5];
  const float* g2  = (const float*)d_in[7];
  const float* be2 = (const float*)d_in[8];
  const float* w3  = (const float*)d_in[9];
  const float* g3  = (const float*)d_in[11];
  const float* be3 = (const float*)d_in[12];
  const float* wf1 = (const float*)d_in[13];
  const float* g4  = (const float*)d_in[15];
  const float* be4 = (const float*)d_in[16];
  const float* wf2 = (const float*)d_in[17];
  const float* bf2 = (const float*)d_in[18];
  float* out = (float*)d_out;

  char* W = (char*)d_ws;
  double* sum   = (double*)W;                 // 2048 dbl
  double* sumsq = sum + 2048;                 // ends 32768
  float*  scale = (float*)(W + 32768);
  float*  shift = scale + 2048;               // ends 49152
  float*    p1   = (float*)   (W + 65536);        // [B][196][64] f32 (dead after norm1)
  float*    c2   = (float*)   (W + 65536);        // [B][196][128] f32 (p1 dead)
  float*    p3   = (float*)   (W + 65536);        // [B][256][49] f32 (c2 dead)
  float*    f1   = (float*)   (W + 65536);        // [1024][2048] f32 (p3 dead)
  ushort_t* a3   = (ushort_t*)(W + 51445760);     // [B][256][49] bf16
  ushort_t* wf1b = (ushort_t*)(W + 77135872);     // [2048][12544] bf16
  ushort_t* a1   = (ushort_t*)(W + 102825984);    // [B][196][64] bf16 (dead after conv2)
  ushort_t* w2b  = (ushort_t*)(W + 128516096);    // [128][576]
  ushort_t* a2   = (ushort_t*)(W + 128663552);    // [B][196][128] bf16
  ushort_t* w3b  = (ushort_t*)(W + 180043776);    // [256][1152]
  float*    pS2  = (float*)   (W + 180633600);    // [1024][128]
  float*    pQ2  = pS2 + 131072;
  float*    pS3  = pQ2 + 131072;                  // [1024][256]
  float*    pQ3  = pS3 + 262144;
  float*    pSF  = pQ3 + 262144;                  // [16][2048]
  float*    pQF  = pSF + 32768;                   // ends ~184 MB

  // ---- layer 1 ----
  k_conv1_pool<<<50176, 256, 0, stream>>>(x, w1, p1);
  hipMemsetAsync(sum, 0, 32768, stream);
  k_stats_cl64<<<dim3(1,128), 256, 0, stream>>>(p1, sum, sumsq, 200704L);
  k_bnparams<<<1, 256, 0, stream>>>(sum, sumsq, g1, be1, scale, shift, 64, 48, 1.0/200704.0);
  k_norm_sign<<<50176, 256, 0, stream>>>(p1, a1, scale, shift, 64, 1, 12845056);
  // ---- layer 2 ----
  k_prep_w2<<<288, 256, 0, stream>>>(w2, w2b);
  k_prep_w3<<<1152, 256, 0, stream>>>(w3, w3b);
  k_conv2_mfma<<<1024, 256, 0, stream>>>(a1, w2b, c2, pS2, pQ2);
  hipMemsetAsync(sum, 0, 32768, stream);
  k_reduce_stats<<<dim3(1,32), 256, 0, stream>>>(pS2, pQ2, sum, sumsq, 128, 1024);
  k_bnparams<<<1, 256, 0, stream>>>(sum, sumsq, g2, be2, scale, shift, 128, 128, 1.0/200704.0);
  k_norm_sign<<<100352, 256, 0, stream>>>(c2, a2, scale, shift, 128, 1, 25690112);
  k_prep_wf1<<<25088, 256, 0, stream>>>(wf1, wf1b);
  // ---- layer 3 ----
  k_conv3_mfma_pool<<<dim3(2, B_), 256, 0, stream>>>(a2, w3b, p3, pS3, pQ3);
  hipMemsetAsync(sum, 0, 32768, stream);
  k_reduce_stats<<<dim3(1,32), 256, 0, stream>>>(pS3, pQ3, sum, sumsq, 256, 1024);
  k_bnparams<<<1, 256, 0, stream>>>(sum, sumsq, g3, be3, scale, shift, 256, 256, 1.0/50176.0);
  k_norm_sign<<<50176, 256, 0, stream>>>(p3, a3, scale, shift, 256, 49, 12845056);
  // ---- fc1 ----
  k_fc1_mfma<<<256, 256, 0, stream>>>(a3, wf1b, f1, pSF, pQF);
  hipMemsetAsync(sum, 0, 32768, stream);
  k_reduce_stats<<<dim3(8,1), 256, 0, stream>>>(pSF, pQF, sum, sumsq, 2048, 16);
  k_bnparams<<<8, 256, 0, stream>>>(sum, sumsq, g4, be4, scale, shift, 2048, 2048, 1.0/1024.0);
  k_norm_htanh<<<8192, 256, 0, stream>>>(f1, scale, shift, 2048, 2097152);
  // ---- fc2 + log_softmax ----
  k_fc2_lsm<<<B_, 256, 0, stream>>>(f1, wf2, bf2, out);
}